// Round 1
// baseline (823.318 us; speedup 1.0000x reference)
//
#include <hip/hip_runtime.h>

// out[i] = l1 * prod_{e: idx[e]==i} factor[e]
// factor = t0c * INV_SQRT_2PI * exp(-0.5 z^2) / t1,  z = (v - t2)/t1
// log(factor) = logC - 0.5 z^2, logC = log(t0c * INV_SQRT_2PI / t1)
// Accumulate logs with atomicAdd into d_out (f32), then exponentiate.

#define INV_SQRT_2PI 0.39894246f  // 1/sqrt(2*3.14159)  (matches reference constant)

__global__ void init_zero_kernel(float* __restrict__ out, int n) {
    int i = blockIdx.x * blockDim.x + threadIdx.x;
    int stride = gridDim.x * blockDim.x;
    for (; i < n; i += stride) out[i] = 0.0f;
}

__global__ void scatter_log_kernel(const int* __restrict__ idx,
                                   const float* __restrict__ vals,
                                   const float* __restrict__ thetas,
                                   float* __restrict__ acc, int n) {
    float t0 = thetas[0], t1 = thetas[1], t2 = thetas[2];
    float t0c = fminf(fmaxf(t0, 0.0f), 1.0f);
    float logC = logf(t0c * INV_SQRT_2PI / t1);
    float inv_t1 = 1.0f / t1;

    int i = blockIdx.x * blockDim.x + threadIdx.x;
    int stride = gridDim.x * blockDim.x;
    for (; i < n; i += stride) {
        float v = vals[i];
        int   k = idx[i];
        float z = (v - t2) * inv_t1;
        float lf = fmaf(-0.5f * z, z, logC);   // logC - 0.5*z*z
        atomicAdd(&acc[k], lf);
    }
}

__global__ void finalize_kernel(float* __restrict__ out,
                                const float* __restrict__ thetas, int n) {
    float t0c = fminf(fmaxf(thetas[0], 0.0f), 1.0f);
    float cond = 1.0f - t0c;
    int i = blockIdx.x * blockDim.x + threadIdx.x;
    int stride = gridDim.x * blockDim.x;
    for (; i < n; i += stride) out[i] = cond * expf(out[i]);
}

extern "C" void kernel_launch(void* const* d_in, const int* in_sizes, int n_in,
                              void* d_out, int out_size, void* d_ws, size_t ws_size,
                              hipStream_t stream) {
    // inputs: [0]=batch (scalar int), [1]=idx (int32), [2]=vals (f32), [3]=thetas (f32 x3)
    const int*   idx    = (const int*)d_in[1];
    const float* vals   = (const float*)d_in[2];
    const float* thetas = (const float*)d_in[3];
    float*       out    = (float*)d_out;

    int n_events = in_sizes[1];
    int n_out    = out_size;

    const int BLOCK = 256;
    // memory-bound: cap blocks, grid-stride the rest
    int grid_out = min((n_out + BLOCK - 1) / BLOCK, 2048);
    int grid_ev  = min((n_events + BLOCK - 1) / BLOCK, 2048);

    init_zero_kernel<<<grid_out, BLOCK, 0, stream>>>(out, n_out);
    scatter_log_kernel<<<grid_ev, BLOCK, 0, stream>>>(idx, vals, thetas, out, n_events);
    finalize_kernel<<<grid_out, BLOCK, 0, stream>>>(out, thetas, n_out);
}